// Round 11
// baseline (321.247 us; speedup 1.0000x reference)
//
#include <hip/hip_runtime.h>
#include <math.h>

#define BB 8
#define TT 256
#define UU 128      // U
#define U1 129      // U+1
#define VV 256
#define ND 384      // anti-diagonals d = t+u
#define WROW 264    // floats per diag row: {blk[u],lbl[u]} pairs u=0..128 + pad
#define NEGF (-1e30f)
#define PF 16       // diagonals per LDS tile
#define REPEAT 3    // diagnostic: x3 repeat -> if k_dp is slow it tops the
                    // rocprof top-5 (beats ~160us harness fills) with counters

// fast logaddexp: inputs finite (sentinel -1e30, never inf/nan)
__device__ __forceinline__ float logaddexpf_(float a, float b) {
    float m = fmaxf(a, b);
    float d = fminf(a, b) - m;
    return m + __logf(1.0f + __expf(d));
}

// wave-wide shift-right-by-1 via DPP (VALU) — lane l gets lane l-1's value
__device__ __forceinline__ float wave_shr1(float x) {
    int r = __builtin_amdgcn_update_dpp(0, __float_as_int(x), 0x138, 0xf, 0xf, true);
    return __int_as_float(r);
}

template <int CTRL>
__device__ __forceinline__ float dppadd(float x) {
    int t = __builtin_amdgcn_update_dpp(0, __float_as_int(x), CTRL, 0xf, 0xf, true);
    return x + __int_as_float(t);
}

// full-wave sum via 6 DPP VALU adds; result broadcast from lane 63
__device__ __forceinline__ float wave_sum(float s) {
    s = dppadd<0x111>(s);   // row_shr:1
    s = dppadd<0x112>(s);   // row_shr:2
    s = dppadd<0x114>(s);   // row_shr:4
    s = dppadd<0x118>(s);   // row_shr:8
    s = dppadd<0x142>(s);   // row_bcast:15
    s = dppadd<0x143>(s);   // row_bcast:31 -> lane 63 = full sum
    return __int_as_float(__builtin_amdgcn_readlane(__float_as_int(s), 63));
}

__device__ __forceinline__ float readlane_f(float x, int l) {
    return __int_as_float(__builtin_amdgcn_readlane(__float_as_int(x), l));
}

// async global->LDS DMA (no VGPR destinations in flight)
__device__ __forceinline__ void gload_lds16(const float* g, float* l) {
    __builtin_amdgcn_global_load_lds(
        (const __attribute__((address_space(1))) void*)g,
        (__attribute__((address_space(3))) void*)l, 16, 0, 0);
}
__device__ __forceinline__ void gload_lds4(const float* g, float* l) {
    __builtin_amdgcn_global_load_lds(
        (const __attribute__((address_space(1))) void*)g,
        (__attribute__((address_space(3))) void*)l, 4, 0, 0);
}

typedef float f4 __attribute__((ext_vector_type(4)));

// Kernel 1 (~18us measured): 4 rows per wave, dead rows skipped, no-max LSE,
// DPP reduce, parallel float2 epilogue; writes compact bD128[b][d] too.
__global__ __launch_bounds__(256) void k_logprobs(
    const float* __restrict__ acts, const int* __restrict__ labels,
    const int* __restrict__ act_lens, const int* __restrict__ label_lens,
    float* __restrict__ wsD, float* __restrict__ bD128)
{
    const int NQUAD = BB * TT * U1 / 4;                 // 66048
    int qid = (blockIdx.x << 2) + (threadIdx.x >> 6);
    if (qid >= NQUAD) return;
    qid = __builtin_amdgcn_readfirstlane(qid);
    int lane = threadIdx.x & 63;
    int wid0 = qid * 4;

    int b = wid0 / (TT * U1);                           // uniform (33024 % 4 == 0)
    int flen = act_lens[b];
    int glen = label_lens[b];

    int tt[4], uu[4]; bool keep[4]; f4 v[4];
    #pragma unroll
    for (int r = 0; r < 4; ++r) {                       // all acts loads first (MLP)
        int wid = wid0 + r;
        int rem = wid - b * (TT * U1);
        int t = rem / U1;
        int u = rem - t * U1;
        tt[r] = t; uu[r] = u;
        keep[r] = (t < flen) && (u <= glen);            // wave-uniform branch
        v[r] = (f4){0.f, 0.f, 0.f, 0.f};
        if (keep[r])
            v[r] = __builtin_nontemporal_load((const f4*)(acts + (size_t)wid * VV) + lane);
    }

    float labv[4];
    #pragma unroll
    for (int r = 0; r < 4; ++r) {                       // label gathers
        labv[r] = 0.f;
        if (keep[r] && uu[r] < UU)
            labv[r] = acts[(size_t)(wid0 + r) * VV + labels[b * UU + uu[r]]];
    }

    float lse[4];
    #pragma unroll
    for (int r = 0; r < 4; ++r) {
        float s = __expf(v[r].x) + __expf(v[r].y) + __expf(v[r].z) + __expf(v[r].w);
        lse[r] = __logf(wave_sum(s));
    }

    // parallel epilogue: lane r owns row r
    float myblk = 0.f, mylbl = 0.f; int myd = 0, myu = 0; bool mykeep = false;
    #pragma unroll
    for (int r = 0; r < 4; ++r) {
        float bs = readlane_f(v[r].x, 0);               // BLANK logit (elem 0, lane 0)
        if (lane == r) {
            myblk = bs - lse[r];
            mylbl = labv[r] - lse[r];                   // u==128: garbage -> row pad, unread
            myd = tt[r] + uu[r]; myu = uu[r]; mykeep = keep[r];
        }
    }
    if (lane < 4 && mykeep) {
        float2 val = make_float2(myblk, mylbl);
        *(float2*)(wsD + (size_t)(b * ND + myd) * WROW + 2 * myu) = val;
        if (myu == UU) bD128[b * ND + myd] = myblk;
    }
}

// one DP step (all lanes). f4 fields: .x=blk[u0] .y=lbl[u0] .z=blk[u1]
// .w=lbl[u1]. bj = blk[128] of diagonal d-1 (broadcast).
__device__ __forceinline__ void dp_step(
    int d, int u0, bool lane0, const f4 wj, float bj,
    float& a0, float& a1, float& a2,
    int dstar, bool isg0, bool isg1, bool isg128, float& saved)
{
    float pm = wave_shr1(a1);           // alpha[u0-1] from lane-1
    float pl = wave_shr1(wj.w);         // lbl[u0-1] from lane-1

    int t0 = d - u0;
    float c1 = (t0 >= 1) ? (a0 + wj.x) : NEGF;
    float c2 = lane0 ? NEGF : (pm + pl);
    float n0 = ((unsigned)t0 <= (TT - 1)) ? logaddexpf_(c1, c2) : NEGF;

    int t1 = t0 - 1;
    float c1b = (t1 >= 1) ? (a1 + wj.z) : NEGF;
    float c2b = a0 + wj.y;
    float n1 = ((unsigned)t1 <= (TT - 1)) ? logaddexpf_(c1b, c2b) : NEGF;

    int t2 = d - 128;                   // uniform
    float c1c = (t2 >= 1) ? (a2 + bj) : NEGF;
    float c2c = a1 + wj.w;
    float n2 = ((unsigned)t2 <= (TT - 1)) ? logaddexpf_(c1c, c2c) : NEGF;

    if (d == dstar) {                   // uniform scalar branch, true once
        float s1 = isg1 ? n1 : (isg128 ? n2 : 0.0f);
        saved = isg0 ? n0 : s1;
    }
    a0 = n0; a1 = n1; a2 = n2;
}

// Kernel 2: one wave per sample. STATIC double-buffered LDS tiles (ldsA/ldsB
// are distinct objects -> alias analysis can prove current-buffer ds_reads
// don't touch the DMA-target buffer; runtime-indexed buffer in R10 could
// not). Phase: issue 16 DMAs into NXT -> sched_barrier -> compute 16 steps
// from CUR -> vmcnt(0). Fixed 24 blocks (12 A/B pairs). REPEAT x3 is a
// diagnostic repeat of the whole DP (identical result each rep).
struct DpState { float a0, a1, a2, saved; };

__device__ __forceinline__ void dp_phase(
    const float* __restrict__ Wd, const float* cur, float* nxt,
    const float* ldsF, int dbase, bool dofill, int u0, bool lane0, int lane,
    int dstar, bool isg0, bool isg1, bool isg128, DpState& st)
{
    if (dofill) {
        const float* Wn = Wd + (size_t)(dbase + PF - 1) * WROW + 4 * lane;
        #pragma unroll
        for (int j = 0; j < PF; ++j)
            gload_lds16(Wn + j * WROW, nxt + j * 256);
    }
    __builtin_amdgcn_sched_barrier(0);  // DMA cluster may not sink into compute

    float b128v = (lane < PF) ? ldsF[dbase - 1 + lane] : 0.f;

    #pragma unroll
    for (int j = 0; j < PF; ++j) {
        f4 wj = *(const f4*)(cur + j * 256 + 4 * lane);
        float bj = readlane_f(b128v, j);
        dp_step(dbase + j, u0, lane0, wj, bj, st.a0, st.a1, st.a2,
                dstar, isg0, isg1, isg128, st.saved);
    }
    asm volatile("s_waitcnt vmcnt(0)" ::: "memory");   // NXT tile resident
}

__global__ __launch_bounds__(64) void k_dp(
    const float* __restrict__ wsD, const float* __restrict__ bD128,
    const int* __restrict__ act_lens, const int* __restrict__ label_lens,
    float* __restrict__ costs)
{
    __shared__ __align__(16) float ldsA[PF * 256];      // 16KB
    __shared__ __align__(16) float ldsB[PF * 256];      // 16KB
    __shared__ __align__(16) float ldsF[ND + 32];       // blk[128] per diag

    int b = blockIdx.x;
    int lane = threadIdx.x;
    const float* Wd = wsD + (size_t)b * ND * WROW;
    const float* Bg = bD128 + b * ND;
    int flen = act_lens[b];
    int glen = label_lens[b];
    int dstar = flen - 1 + glen;        // in [191, 383]

    const int u0 = 2 * lane;
    const bool lane0  = (lane == 0);
    const bool isg0   = (u0 == glen);
    const bool isg1   = (u0 + 1 == glen);
    const bool isg128 = (lane == 63) && (glen == 128);
    const bool have   = isg0 | isg1 | isg128;

    // ldsF once (drained below together with rep-0 prologue fill)
    #pragma unroll
    for (int k = 0; k < 6; ++k)
        gload_lds4(Bg + k * 64 + lane, &ldsF[k * 64]);

    DpState st;
    #pragma unroll 1
    for (int rep = 0; rep < REPEAT; ++rep) {
        // prologue: rows 0..15 -> ldsA
        #pragma unroll
        for (int j = 0; j < PF; ++j)
            gload_lds16(Wd + j * WROW + 4 * lane, &ldsA[j * 256]);
        asm volatile("s_waitcnt vmcnt(0)" ::: "memory");

        st.a0 = lane0 ? 0.0f : NEGF;
        st.a1 = NEGF;
        st.a2 = NEGF;
        st.saved = 0.0f;

        #pragma unroll 1
        for (int pi = 0; pi < 12; ++pi) {
            int dbase = 1 + pi * 32;
            // phase A: compute [dbase, dbase+16) from ldsA, fill ldsB
            dp_phase(Wd, ldsA, ldsB, ldsF, dbase, true,
                     u0, lane0, lane, dstar, isg0, isg1, isg128, st);
            // phase B: compute [dbase+16, dbase+32) from ldsB, fill ldsA
            dp_phase(Wd, ldsB, ldsA, ldsF, dbase + PF, pi < 11,
                     u0, lane0, lane, dstar, isg0, isg1, isg128, st);
        }
    }

    if (have) {
        float blkv = Wd[(size_t)dstar * WROW + 2 * glen];
        costs[b] = -(st.saved + blkv);
    }
}

__global__ void k_sum(const float* __restrict__ costs, float* __restrict__ out)
{
    if (threadIdx.x == 0 && blockIdx.x == 0) {
        float s = 0.0f;
        for (int i = 0; i < BB; ++i) s += costs[i];
        out[0] = s;
    }
}

extern "C" void kernel_launch(void* const* d_in, const int* in_sizes, int n_in,
                              void* d_out, int out_size, void* d_ws, size_t ws_size,
                              hipStream_t stream) {
    const float* acts      = (const float*)d_in[0];
    const int*   labels    = (const int*)d_in[1];
    const int*   act_lens  = (const int*)d_in[2];
    const int*   label_lens= (const int*)d_in[3];
    float* out = (float*)d_out;

    float* wsD   = (float*)d_ws;                       // 8*384*264 floats = 3.24 MB
    float* bD128 = wsD + (size_t)BB * ND * WROW;       // 8*384 floats
    float* costs = (float*)d_ws + (8u << 20);          // 32 MB in: clear of any overrun

    const int NQUAD = BB * TT * U1 / 4;                // 66048 waves
    int blocks = NQUAD / 4;                            // 16512 (exact)

    k_logprobs<<<blocks, 256, 0, stream>>>(acts, labels, act_lens, label_lens, wsD, bD128);
    k_dp<<<BB, 64, 0, stream>>>(wsD, bD128, act_lens, label_lens, costs);
    k_sum<<<1, 64, 0, stream>>>(costs, out);
}

// Round 13
// 114.299 us; speedup vs baseline: 2.8106x; 2.8106x over previous
//
#include <hip/hip_runtime.h>
#include <math.h>

#define BB 8
#define TT 256
#define UU 128      // U
#define U1 129      // U+1
#define VV 256
#define ND 384      // anti-diagonals d = t+u
#define WROW 264    // floats per diag row: {blk[u],lbl[u]} pairs u=0..128 + pad
#define NEGF (-1e30f)
#define PF 16       // diagonals per ring slot
#define NPROD 3     // producer waves (waves 1..3); wave 0 = consumer

// fast logaddexp: inputs finite (sentinel -1e30, never inf/nan)
__device__ __forceinline__ float logaddexpf_(float a, float b) {
    float m = fmaxf(a, b);
    float d = fminf(a, b) - m;
    return m + __logf(1.0f + __expf(d));
}

// wave-wide shift-right-by-1 via DPP (VALU) — lane l gets lane l-1's value
__device__ __forceinline__ float wave_shr1(float x) {
    int r = __builtin_amdgcn_update_dpp(0, __float_as_int(x), 0x138, 0xf, 0xf, true);
    return __int_as_float(r);
}

template <int CTRL>
__device__ __forceinline__ float dppadd(float x) {
    int t = __builtin_amdgcn_update_dpp(0, __float_as_int(x), CTRL, 0xf, 0xf, true);
    return x + __int_as_float(t);
}

// full-wave sum via 6 DPP VALU adds; result broadcast from lane 63
__device__ __forceinline__ float wave_sum(float s) {
    s = dppadd<0x111>(s);   // row_shr:1
    s = dppadd<0x112>(s);   // row_shr:2
    s = dppadd<0x114>(s);   // row_shr:4
    s = dppadd<0x118>(s);   // row_shr:8
    s = dppadd<0x142>(s);   // row_bcast:15
    s = dppadd<0x143>(s);   // row_bcast:31 -> lane 63 = full sum
    return __int_as_float(__builtin_amdgcn_readlane(__float_as_int(s), 63));
}

__device__ __forceinline__ float readlane_f(float x, int l) {
    return __int_as_float(__builtin_amdgcn_readlane(__float_as_int(x), l));
}

typedef float f4 __attribute__((ext_vector_type(4)));

// Kernel 1 (~18us measured, L3-resident across replays): 4 rows per wave,
// dead rows skipped, no-max LSE, DPP reduce, parallel float2 epilogue;
// writes compact bD128[b][d] = blk[t][128] as well.
__global__ __launch_bounds__(256) void k_logprobs(
    const float* __restrict__ acts, const int* __restrict__ labels,
    const int* __restrict__ act_lens, const int* __restrict__ label_lens,
    float* __restrict__ wsD, float* __restrict__ bD128)
{
    const int NQUAD = BB * TT * U1 / 4;                 // 66048
    int qid = (blockIdx.x << 2) + (threadIdx.x >> 6);
    if (qid >= NQUAD) return;
    qid = __builtin_amdgcn_readfirstlane(qid);
    int lane = threadIdx.x & 63;
    int wid0 = qid * 4;

    int b = wid0 / (TT * U1);                           // uniform (33024 % 4 == 0)
    int flen = act_lens[b];
    int glen = label_lens[b];

    int tt[4], uu[4]; bool keep[4]; f4 v[4];
    #pragma unroll
    for (int r = 0; r < 4; ++r) {                       // all acts loads first (MLP)
        int wid = wid0 + r;
        int rem = wid - b * (TT * U1);
        int t = rem / U1;
        int u = rem - t * U1;
        tt[r] = t; uu[r] = u;
        keep[r] = (t < flen) && (u <= glen);            // wave-uniform branch
        v[r] = (f4){0.f, 0.f, 0.f, 0.f};
        if (keep[r])
            v[r] = __builtin_nontemporal_load((const f4*)(acts + (size_t)wid * VV) + lane);
    }

    float labv[4];
    #pragma unroll
    for (int r = 0; r < 4; ++r) {                       // label gathers
        labv[r] = 0.f;
        if (keep[r] && uu[r] < UU)
            labv[r] = acts[(size_t)(wid0 + r) * VV + labels[b * UU + uu[r]]];
    }

    float lse[4];
    #pragma unroll
    for (int r = 0; r < 4; ++r) {
        float s = __expf(v[r].x) + __expf(v[r].y) + __expf(v[r].z) + __expf(v[r].w);
        lse[r] = __logf(wave_sum(s));
    }

    // parallel epilogue: lane r owns row r
    float myblk = 0.f, mylbl = 0.f; int myd = 0, myu = 0; bool mykeep = false;
    #pragma unroll
    for (int r = 0; r < 4; ++r) {
        float bs = readlane_f(v[r].x, 0);               // BLANK logit (elem 0, lane 0)
        if (lane == r) {
            myblk = bs - lse[r];
            mylbl = labv[r] - lse[r];                   // u==128: garbage -> row pad, unread
            myd = tt[r] + uu[r]; myu = uu[r]; mykeep = keep[r];
        }
    }
    if (lane < 4 && mykeep) {
        float2 val = make_float2(myblk, mylbl);
        *(float2*)(wsD + (size_t)(b * ND + myd) * WROW + 2 * myu) = val;
        if (myu == UU) bD128[b * ND + myd] = myblk;
    }
}

// one DP step (consumer wave). f4 fields: .x=blk[u0] .y=lbl[u0] .z=blk[u1]
// .w=lbl[u1] — all from diagonal d-1. bj = blk[128] of diagonal d-1.
__device__ __forceinline__ void dp_step(
    int d, int u0, bool lane0, const f4 wj, float bj,
    float& a0, float& a1, float& a2,
    int dstar, bool isg0, bool isg1, bool isg128, float& saved)
{
    float pm = wave_shr1(a1);           // alpha[u0-1] from lane-1
    float pl = wave_shr1(wj.w);         // lbl[u0-1] from lane-1

    int t0 = d - u0;
    float c1 = (t0 >= 1) ? (a0 + wj.x) : NEGF;
    float c2 = lane0 ? NEGF : (pm + pl);
    float n0 = ((unsigned)t0 <= (TT - 1)) ? logaddexpf_(c1, c2) : NEGF;

    int t1 = t0 - 1;
    float c1b = (t1 >= 1) ? (a1 + wj.z) : NEGF;
    float c2b = a0 + wj.y;
    float n1 = ((unsigned)t1 <= (TT - 1)) ? logaddexpf_(c1b, c2b) : NEGF;

    int t2 = d - 128;                   // uniform
    float c1c = (t2 >= 1) ? (a2 + bj) : NEGF;
    float c2c = a1 + wj.w;
    float n2 = ((unsigned)t2 <= (TT - 1)) ? logaddexpf_(c1c, c2c) : NEGF;

    if (d == dstar) {                   // uniform scalar branch, true once
        float s1 = isg1 ? n1 : (isg128 ? n2 : 0.0f);
        saved = isg0 ? n0 : s1;
    }
    a0 = n0; a1 = n1; a2 = n2;
}

// Kernel 2: producer/consumer. 4 waves per sample: wave 0 = serial DP
// consumer; waves 1-3 reg-stage diag rows into a 4-slot LDS ring, 2 phases
// ahead. TILE CONVENTION (the R12 bug): slot for phase p holds diag rows
// dbase(p)-1+j, j=0..15 — step d consumes row d-1. Prologue fills diags
// 0..31; steady-state phase p fills diags fbase-1+j for phase p+2.
__global__ __launch_bounds__(256) void k_dp(
    const float* __restrict__ wsD, const float* __restrict__ bD128,
    const int* __restrict__ act_lens, const int* __restrict__ label_lens,
    float* __restrict__ costs)
{
    __shared__ __align__(16) float ring[4][PF * 256];   // 4 x 16KB
    __shared__ __align__(16) float ldsF[ND + 32];       // blk[128] per diag

    int b = blockIdx.x;
    int tid = threadIdx.x;
    int wave = tid >> 6;
    int lane = tid & 63;
    const float* Wd = wsD + (size_t)b * ND * WROW;
    const float* Bg = bD128 + b * ND;
    int flen = act_lens[b];
    int glen = label_lens[b];
    int dstar = flen - 1 + glen;        // in [191, 383]
    int pmax  = (dstar - 1) / PF;       // last phase index (>= 11 always)

    const int u0 = 2 * lane;
    const bool lane0  = (lane == 0);
    const bool isg0   = (u0 == glen);
    const bool isg1   = (u0 + 1 == glen);
    const bool isg128 = (lane == 63) && (glen == 128);
    const bool have   = isg0 | isg1 | isg128;

    // prologue: producers fill slots 0,1 with diags 0..31; wave 0 fills ldsF
    if (wave == 0) {
        #pragma unroll
        for (int k = 0; k < 6; ++k)
            ldsF[k * 64 + lane] = Bg[k * 64 + lane];
    } else {
        for (int j = wave - 1; j < 2 * PF; j += NPROD) {
            int d2 = j;                                  // diag j (0..31)
            f4 v = *(const f4*)(Wd + (size_t)d2 * WROW + 4 * lane);
            *(f4*)&ring[j >> 4][(j & 15) * 256 + 4 * lane] = v;
        }
    }
    __syncthreads();

    float a0 = lane0 ? 0.0f : NEGF;     // u = 2*lane
    float a1 = NEGF;                    // u = 2*lane+1
    float a2 = NEGF;                    // u = 128 (lane 63 only meaningful)
    float saved = 0.0f;

    #pragma unroll 1
    for (int p = 0; p <= pmax; ++p) {
        int dbase = 1 + p * PF;
        if (wave == 0) {
            // consumer: 16 DP steps from slot p%4 (row j = diag dbase-1+j)
            const float* slot = ring[p & 3];
            float b128v = (lane < PF) ? ldsF[dbase - 1 + lane] : 0.f;
            #pragma unroll
            for (int j = 0; j < PF; ++j) {
                f4 wj = *(const f4*)(slot + j * 256 + 4 * lane);
                float bj = readlane_f(b128v, j);
                dp_step(dbase + j, u0, lane0, wj, bj, a0, a1, a2,
                        dstar, isg0, isg1, isg128, saved);
            }
        } else {
            // producers: fill slot (p+2)%4 with diags fbase-1+j (phase p+2)
            int fbase = dbase + 2 * PF;                  // dbase of phase p+2
            if (fbase <= dstar) {                        // phase p+2 will run
                float* slot = ring[(p + 2) & 3];
                for (int j = wave - 1; j < PF; j += NPROD) {
                    int d2 = fbase - 1 + j;
                    if (d2 > ND - 1) d2 = ND - 1;        // clamp tail (dead steps)
                    f4 v = *(const f4*)(Wd + (size_t)d2 * WROW + 4 * lane);
                    *(f4*)&slot[j * 256 + 4 * lane] = v;
                }
            }
        }
        __syncthreads();
    }

    if (wave == 0 && have) {
        float blkv = Wd[(size_t)dstar * WROW + 2 * glen];
        costs[b] = -(saved + blkv);
    }
}

__global__ void k_sum(const float* __restrict__ costs, float* __restrict__ out)
{
    if (threadIdx.x == 0 && blockIdx.x == 0) {
        float s = 0.0f;
        for (int i = 0; i < BB; ++i) s += costs[i];
        out[0] = s;
    }
}

extern "C" void kernel_launch(void* const* d_in, const int* in_sizes, int n_in,
                              void* d_out, int out_size, void* d_ws, size_t ws_size,
                              hipStream_t stream) {
    const float* acts      = (const float*)d_in[0];
    const int*   labels    = (const int*)d_in[1];
    const int*   act_lens  = (const int*)d_in[2];
    const int*   label_lens= (const int*)d_in[3];
    float* out = (float*)d_out;

    float* wsD   = (float*)d_ws;                       // 8*384*264 floats = 3.24 MB
    float* bD128 = wsD + (size_t)BB * ND * WROW;       // 8*384 floats
    float* costs = (float*)d_ws + (8u << 20);          // 32 MB in: clear of any overrun

    const int NQUAD = BB * TT * U1 / 4;                // 66048 waves
    int blocks = NQUAD / 4;                            // 16512 (exact)

    k_logprobs<<<blocks, 256, 0, stream>>>(acts, labels, act_lens, label_lens, wsD, bD128);
    k_dp<<<BB, 256, 0, stream>>>(wsD, bD128, act_lens, label_lens, costs);
    k_sum<<<1, 64, 0, stream>>>(costs, out);
}

// Round 14
// 106.689 us; speedup vs baseline: 3.0111x; 1.0713x over previous
//
#include <hip/hip_runtime.h>
#include <math.h>

#define BB 8
#define TT 256
#define UU 128      // U
#define U1 129      // U+1
#define VV 256
#define ND 384      // anti-diagonals d = t+u
#define WROW 264    // floats per diag row: {blk[u],lbl[u]} pairs u=0..128 + pad
#define NEGF (-1e30f)
#define PF 16       // diagonals per ring slot
#define NPROD 3     // producer waves (waves 1..3); wave 0 = consumer

// fast logaddexp: inputs finite (sentinel -1e30, never inf/nan)
__device__ __forceinline__ float logaddexpf_(float a, float b) {
    float m = fmaxf(a, b);
    float d = fminf(a, b) - m;
    return m + __logf(1.0f + __expf(d));
}

// wave-wide shift-right-by-1 via DPP (VALU) — lane l gets lane l-1's value
__device__ __forceinline__ float wave_shr1(float x) {
    int r = __builtin_amdgcn_update_dpp(0, __float_as_int(x), 0x138, 0xf, 0xf, true);
    return __int_as_float(r);
}

template <int CTRL>
__device__ __forceinline__ float dppadd(float x) {
    int t = __builtin_amdgcn_update_dpp(0, __float_as_int(x), CTRL, 0xf, 0xf, true);
    return x + __int_as_float(t);
}

// full-wave sum via 6 DPP VALU adds; result broadcast from lane 63
__device__ __forceinline__ float wave_sum(float s) {
    s = dppadd<0x111>(s);   // row_shr:1
    s = dppadd<0x112>(s);   // row_shr:2
    s = dppadd<0x114>(s);   // row_shr:4
    s = dppadd<0x118>(s);   // row_shr:8
    s = dppadd<0x142>(s);   // row_bcast:15
    s = dppadd<0x143>(s);   // row_bcast:31 -> lane 63 = full sum
    return __int_as_float(__builtin_amdgcn_readlane(__float_as_int(s), 63));
}

__device__ __forceinline__ float readlane_f(float x, int l) {
    return __int_as_float(__builtin_amdgcn_readlane(__float_as_int(x), l));
}

typedef float f4 __attribute__((ext_vector_type(4)));

// Kernel 1 (~18us measured): 4 rows per wave, dead rows skipped, no-max LSE,
// DPP reduce, parallel float2 epilogue; writes compact bD128[b][d] too.
__global__ __launch_bounds__(256) void k_logprobs(
    const float* __restrict__ acts, const int* __restrict__ labels,
    const int* __restrict__ act_lens, const int* __restrict__ label_lens,
    float* __restrict__ wsD, float* __restrict__ bD128)
{
    const int NQUAD = BB * TT * U1 / 4;                 // 66048
    int qid = (blockIdx.x << 2) + (threadIdx.x >> 6);
    if (qid >= NQUAD) return;
    qid = __builtin_amdgcn_readfirstlane(qid);
    int lane = threadIdx.x & 63;
    int wid0 = qid * 4;

    int b = wid0 / (TT * U1);                           // uniform (33024 % 4 == 0)
    int flen = act_lens[b];
    int glen = label_lens[b];

    int tt[4], uu[4]; bool keep[4]; f4 v[4];
    #pragma unroll
    for (int r = 0; r < 4; ++r) {                       // all acts loads first (MLP)
        int wid = wid0 + r;
        int rem = wid - b * (TT * U1);
        int t = rem / U1;
        int u = rem - t * U1;
        tt[r] = t; uu[r] = u;
        keep[r] = (t < flen) && (u <= glen);            // wave-uniform branch
        v[r] = (f4){0.f, 0.f, 0.f, 0.f};
        if (keep[r])
            v[r] = __builtin_nontemporal_load((const f4*)(acts + (size_t)wid * VV) + lane);
    }

    float labv[4];
    #pragma unroll
    for (int r = 0; r < 4; ++r) {                       // label gathers
        labv[r] = 0.f;
        if (keep[r] && uu[r] < UU)
            labv[r] = acts[(size_t)(wid0 + r) * VV + labels[b * UU + uu[r]]];
    }

    float lse[4];
    #pragma unroll
    for (int r = 0; r < 4; ++r) {
        float s = __expf(v[r].x) + __expf(v[r].y) + __expf(v[r].z) + __expf(v[r].w);
        lse[r] = __logf(wave_sum(s));
    }

    // parallel epilogue: lane r owns row r
    float myblk = 0.f, mylbl = 0.f; int myd = 0, myu = 0; bool mykeep = false;
    #pragma unroll
    for (int r = 0; r < 4; ++r) {
        float bs = readlane_f(v[r].x, 0);               // BLANK logit (elem 0, lane 0)
        if (lane == r) {
            myblk = bs - lse[r];
            mylbl = labv[r] - lse[r];                   // u==128: garbage -> row pad, unread
            myd = tt[r] + uu[r]; myu = uu[r]; mykeep = keep[r];
        }
    }
    if (lane < 4 && mykeep) {
        float2 val = make_float2(myblk, mylbl);
        *(float2*)(wsD + (size_t)(b * ND + myd) * WROW + 2 * myu) = val;
        if (myu == UU) bD128[b * ND + myd] = myblk;
    }
}

// one DP step (consumer wave). f4 fields: .x=blk[u0] .y=lbl[u0] .z=blk[u1]
// .w=lbl[u1] — all from diagonal d-1. bj = blk[128] of diagonal d-1.
__device__ __forceinline__ void dp_step(
    int d, int u0, bool lane0, const f4 wj, float bj,
    float& a0, float& a1, float& a2,
    int dstar, bool isg0, bool isg1, bool isg128, float& saved)
{
    float pm = wave_shr1(a1);           // alpha[u0-1] from lane-1
    float pl = wave_shr1(wj.w);         // lbl[u0-1] from lane-1

    int t0 = d - u0;
    float c1 = (t0 >= 1) ? (a0 + wj.x) : NEGF;
    float c2 = lane0 ? NEGF : (pm + pl);
    float n0 = ((unsigned)t0 <= (TT - 1)) ? logaddexpf_(c1, c2) : NEGF;

    int t1 = t0 - 1;
    float c1b = (t1 >= 1) ? (a1 + wj.z) : NEGF;
    float c2b = a0 + wj.y;
    float n1 = ((unsigned)t1 <= (TT - 1)) ? logaddexpf_(c1b, c2b) : NEGF;

    int t2 = d - 128;                   // uniform
    float c1c = (t2 >= 1) ? (a2 + bj) : NEGF;
    float c2c = a1 + wj.w;
    float n2 = ((unsigned)t2 <= (TT - 1)) ? logaddexpf_(c1c, c2c) : NEGF;

    if (d == dstar) {                   // uniform scalar branch, true once
        float s1 = isg1 ? n1 : (isg128 ? n2 : 0.0f);
        saved = isg0 ? n0 : s1;
    }
    a0 = n0; a1 = n1; a2 = n2;
}

// Kernel 2: producer/consumer with BATCHED issue (fix for R13's ~9k cyc/phase
// = per-iteration serialized load->ds_write latency). Producers: 6-load
// cluster (constant-indexed regs) -> sched_barrier -> 6-write cluster: ONE
// ~900cy latency per phase, overlapped across 3 waves + consumer compute.
// Consumer: all 16 ds_read_b128 hoisted to phase top (issue-limited, not
// 16x120cy serial). Ring/barrier discipline identical to R13 (verified).
// Slot for phase p holds diag rows dbase(p)-1+j; step d consumes row d-1.
__global__ __launch_bounds__(256) void k_dp(
    const float* __restrict__ wsD, const float* __restrict__ bD128,
    const int* __restrict__ act_lens, const int* __restrict__ label_lens,
    float* __restrict__ costs)
{
    __shared__ __align__(16) float ring[4][PF * 256];   // 4 x 16KB
    __shared__ __align__(16) float ldsF[ND + 32];       // blk[128] per diag

    int b = blockIdx.x;
    int tid = threadIdx.x;
    int wave = tid >> 6;
    int lane = tid & 63;
    const float* Wd = wsD + (size_t)b * ND * WROW;
    const float* Bg = bD128 + b * ND;
    int flen = act_lens[b];
    int glen = label_lens[b];
    int dstar = flen - 1 + glen;        // in [191, 383]
    int pmax  = (dstar - 1) / PF;       // last phase index (>= 11 always)

    const int u0 = 2 * lane;
    const bool lane0  = (lane == 0);
    const bool isg0   = (u0 == glen);
    const bool isg1   = (u0 + 1 == glen);
    const bool isg128 = (lane == 63) && (glen == 128);
    const bool have   = isg0 | isg1 | isg128;

    // prologue: producers batch-fill slots 0,1 with diags 0..31 (11 rows
    // each, chunked, one latency); wave 0 fills ldsF.
    if (wave == 0) {
        #pragma unroll
        for (int k = 0; k < 6; ++k)
            ldsF[k * 64 + lane] = Bg[k * 64 + lane];
    } else {
        f4 pv[11];
        #pragma unroll
        for (int k = 0; k < 11; ++k) {
            int r = (wave - 1) * 11 + k; if (r > 31) r = 31;
            pv[k] = *(const f4*)(Wd + (size_t)r * WROW + 4 * lane);
        }
        __builtin_amdgcn_sched_barrier(0);   // keep load cluster above writes
        #pragma unroll
        for (int k = 0; k < 11; ++k) {
            int r = (wave - 1) * 11 + k; if (r > 31) r = 31;
            *(f4*)&ring[r >> 4][(r & 15) * 256 + 4 * lane] = pv[k];
        }
    }
    __syncthreads();

    float a0 = lane0 ? 0.0f : NEGF;     // u = 2*lane
    float a1 = NEGF;                    // u = 2*lane+1
    float a2 = NEGF;                    // u = 128 (lane 63 only meaningful)
    float saved = 0.0f;

    #pragma unroll 1
    for (int p = 0; p <= pmax; ++p) {
        int dbase = 1 + p * PF;
        if (wave == 0) {
            // consumer: hoist 16 LDS reads, then 16 DP steps
            const float* slot = ring[p & 3];
            float b128v = (lane < PF) ? ldsF[dbase - 1 + lane] : 0.f;
            f4 wreg[PF];
            #pragma unroll
            for (int j = 0; j < PF; ++j)
                wreg[j] = *(const f4*)(slot + j * 256 + 4 * lane);
            #pragma unroll
            for (int j = 0; j < PF; ++j) {
                float bj = readlane_f(b128v, j);
                dp_step(dbase + j, u0, lane0, wreg[j], bj, a0, a1, a2,
                        dstar, isg0, isg1, isg128, saved);
            }
        } else {
            // producers: batch-fill slot (p+2)%4 (diags fbase-1+j, phase p+2)
            int fbase = dbase + 2 * PF;                  // dbase of phase p+2
            if (fbase <= dstar) {                        // phase p+2 will run
                float* slot = ring[(p + 2) & 3];
                f4 pv[6];
                #pragma unroll
                for (int k = 0; k < 6; ++k) {
                    int r = (wave - 1) * 6 + k; if (r > 15) r = 15;
                    int d2 = fbase - 1 + r; if (d2 > ND - 1) d2 = ND - 1;
                    pv[k] = *(const f4*)(Wd + (size_t)d2 * WROW + 4 * lane);
                }
                __builtin_amdgcn_sched_barrier(0);
                #pragma unroll
                for (int k = 0; k < 6; ++k) {
                    int r = (wave - 1) * 6 + k; if (r > 15) r = 15;
                    *(f4*)&slot[r * 256 + 4 * lane] = pv[k];
                }
            }
        }
        __syncthreads();
    }

    if (wave == 0 && have) {
        float blkv = Wd[(size_t)dstar * WROW + 2 * glen];
        costs[b] = -(saved + blkv);
    }
}

__global__ void k_sum(const float* __restrict__ costs, float* __restrict__ out)
{
    if (threadIdx.x == 0 && blockIdx.x == 0) {
        float s = 0.0f;
        for (int i = 0; i < BB; ++i) s += costs[i];
        out[0] = s;
    }
}

extern "C" void kernel_launch(void* const* d_in, const int* in_sizes, int n_in,
                              void* d_out, int out_size, void* d_ws, size_t ws_size,
                              hipStream_t stream) {
    const float* acts      = (const float*)d_in[0];
    const int*   labels    = (const int*)d_in[1];
    const int*   act_lens  = (const int*)d_in[2];
    const int*   label_lens= (const int*)d_in[3];
    float* out = (float*)d_out;

    float* wsD   = (float*)d_ws;                       // 8*384*264 floats = 3.24 MB
    float* bD128 = wsD + (size_t)BB * ND * WROW;       // 8*384 floats
    float* costs = (float*)d_ws + (8u << 20);          // 32 MB in: clear of any overrun

    const int NQUAD = BB * TT * U1 / 4;                // 66048 waves
    int blocks = NQUAD / 4;                            // 16512 (exact)

    k_logprobs<<<blocks, 256, 0, stream>>>(acts, labels, act_lens, label_lens, wsD, bD128);
    k_dp<<<BB, 256, 0, stream>>>(wsD, bD128, act_lens, label_lens, costs);
    k_sum<<<1, 64, 0, stream>>>(costs, out);
}